// Round 4
// baseline (450.636 us; speedup 1.0000x reference)
//
#include <hip/hip_runtime.h>

// GNN: N=50000 nodes, E=800000 edges, IN=128, HID=64, OUT=128, EH=32, 3 etypes, 2 ntypes.
//
// Strategy:
//   feat @ eW[e] = nf[src] @ eW[e][:IN] + nf[dst] @ eW[e][IN:]
//   => per-node projections P[n][192], per-edge work = 32 adds + relu + reg accumulation
//      (gather over CSR-by-dst). Node MLP type-partitioned.
//
// R1: multi-block scan (was 77 us single-block).
// R2: mlp: type-partitioned + b128 LDS inner loop (was LDS-pipe-bound at 50% VALUBusy).
// R3: CSR build: count+fill (both scattered-atomic passes, ~115 us) -> passA
//     (8-way replicated rank atomics, coalesced rank write) + passB (atomic-free
//     scatter). proj: 32-node tile + transposed-W b128 inner loop (was 14 scalar
//     b32/kk, grid-starved at 782 blocks).

// ---------------- CSR build ----------------

// passA: per-edge rank within (dst, replica). r = blockIdx&7 recomputed as (i>>8)&7.
__global__ __launch_bounds__(256) void rank_kernel(const int* __restrict__ dst,
                                                   int* __restrict__ deg8,
                                                   int* __restrict__ rank, int E) {
  int i = blockIdx.x * 256 + threadIdx.x;
  if (i < E) {
    int d = dst[i];
    int r = (i >> 8) & 7;
    rank[i] = atomicAdd(&deg8[d * 8 + r], 1);
  }
}

// block-local exclusive scan over node degrees; folds 8 replica counts per node
// into total degree + in-place exclusive replica offsets.
__global__ __launch_bounds__(256) void scan1_kernel(int* __restrict__ deg8,
                                                    int* __restrict__ rowstart,
                                                    int* __restrict__ bsum, int n) {
  __shared__ int tmp[256];
  int t = threadIdx.x;
  int base = blockIdx.x * 1024 + t * 4;
  int vdeg[4];
#pragma unroll
  for (int q = 0; q < 4; ++q) {
    int v = base + q;
    int d = 0;
    if (v < n) {
      int4 a = *(int4*)(deg8 + (size_t)v * 8);
      int4 b = *(int4*)(deg8 + (size_t)v * 8 + 4);
      int p1 = a.x, p2 = p1 + a.y, p3 = p2 + a.z, p4 = p3 + a.w;
      int p5 = p4 + b.x, p6 = p5 + b.y, p7 = p6 + b.z;
      d = p7 + b.w;
      *(int4*)(deg8 + (size_t)v * 8) = make_int4(0, p1, p2, p3);
      *(int4*)(deg8 + (size_t)v * 8 + 4) = make_int4(p4, p5, p6, p7);
    }
    vdeg[q] = d;
  }
  int s = vdeg[0] + vdeg[1] + vdeg[2] + vdeg[3];
  tmp[t] = s;
  __syncthreads();
  for (int off = 1; off < 256; off <<= 1) {
    int u = (t >= off) ? tmp[t - off] : 0;
    __syncthreads();
    tmp[t] += u;
    __syncthreads();
  }
  int excl = tmp[t] - s;
  if (base < n)     rowstart[base]     = excl;
  if (base + 1 < n) rowstart[base + 1] = excl + vdeg[0];
  if (base + 2 < n) rowstart[base + 2] = excl + vdeg[0] + vdeg[1];
  if (base + 3 < n) rowstart[base + 3] = excl + vdeg[0] + vdeg[1] + vdeg[2];
  if (t == 255) bsum[blockIdx.x] = tmp[255];
}

// scan of <=64 block sums in one wave; also writes rowstart[n] = total
__global__ __launch_bounds__(64) void scan2_kernel(const int* __restrict__ bsum,
                                                   int* __restrict__ boff, int nb,
                                                   int* __restrict__ rowstart, int n) {
  int lane = threadIdx.x;
  int v = (lane < nb) ? bsum[lane] : 0;
  int incl = v;
  for (int off = 1; off < 64; off <<= 1) {
    int u = __shfl_up(incl, off, 64);
    if (lane >= off) incl += u;
  }
  if (lane < nb) boff[lane] = incl - v;
  if (lane == 63) rowstart[n] = incl;
}

__global__ __launch_bounds__(256) void scan3_kernel(int* __restrict__ rowstart,
                                                    const int* __restrict__ boff, int n) {
  int i = blockIdx.x * 256 + threadIdx.x;
  if (i < n) rowstart[i] += boff[i >> 10];
}

// passB: atomic-free scatter. pos = rowstart[d] + repoff[d][r] + rank.
__global__ __launch_bounds__(256) void fill_kernel(const int* __restrict__ src,
                                                   const int* __restrict__ dst,
                                                   const int* __restrict__ etype,
                                                   const int* __restrict__ rank,
                                                   const int* __restrict__ rowstart,
                                                   const int* __restrict__ deg8,
                                                   int* __restrict__ edata, int E) {
  int i = blockIdx.x * 256 + threadIdx.x;
  if (i < E) {
    int d = dst[i];
    int r = (i >> 8) & 7;
    int pos = rowstart[d] + deg8[d * 8 + r] + rank[i];
    edata[pos] = (etype[i] << 16) | src[i];  // src < 65536 OK (N=50000)
  }
}

// ---------------- node partition by type (unordered index lists) ----------------

__global__ __launch_bounds__(256) void partition_kernel(const int* __restrict__ ntype,
                                                        int* __restrict__ idxbuf,
                                                        int* __restrict__ tcnt,
                                                        int n, int ncap) {
  int i = blockIdx.x * 256 + threadIdx.x;
  int lane = threadIdx.x & 63;
  int t = (i < n) ? ntype[i] : -1;
  unsigned long long m0 = __ballot(t == 0);
  unsigned long long m1 = __ballot(t == 1);
  int b0 = 0, b1 = 0;
  if (lane == 0) {
    b0 = atomicAdd(&tcnt[0], (int)__popcll(m0));
    b1 = atomicAdd(&tcnt[1], (int)__popcll(m1));
  }
  b0 = __shfl(b0, 0);
  b1 = __shfl(b1, 0);
  unsigned long long below = (1ull << lane) - 1ull;
  if (t == 0) idxbuf[b0 + (int)__popcll(m0 & below)] = i;
  else if (t == 1) idxbuf[ncap + b1 + (int)__popcll(m1 & below)] = i;
}

// ---------------- node projection GEMM: P[N,192] = X[N,IN] @ W2[IN,192] ----------------
// 32-node x 192 tile, K-chunk 32. Ws transposed [j][kk] pitch 36; all-b128 inner loop.
// Thread: 4 nodes (broadcast xv) x 6 outputs.

template <int IN>
__global__ __launch_bounds__(256) void proj_kernel(const float* __restrict__ X,
                                                   const float* __restrict__ eW,
                                                   float* __restrict__ P, int n) {
  __shared__ float Xs[32 * 32];    // [node][kk]  4 KB
  __shared__ float Ws[192 * 36];   // [j][kk]     27.6 KB
  const int tx = threadIdx.x;
  const int t32 = tx & 31;
  const int ng = tx >> 5;  // 8 groups x 4 nodes
  const int base = blockIdx.x * 32;
  float acc[4][6];
#pragma unroll
  for (int i = 0; i < 4; ++i)
#pragma unroll
    for (int c = 0; c < 6; ++c) acc[i][c] = 0.f;

  for (int k0 = 0; k0 < IN; k0 += 32) {
    {  // stage X: one float4 per thread
      int i = tx >> 3, kk4 = (tx & 7) * 4;
      int node = base + i;
      float4 v = make_float4(0.f, 0.f, 0.f, 0.f);
      if (node < n) v = *(const float4*)(X + (size_t)node * IN + k0 + kk4);
      *(float4*)(Xs + i * 32 + kk4) = v;
    }
    // stage W transposed: read float4 over j (coalesced), write [j][kk] pitch 36
    for (int id = tx; id < 1536; id += 256) {
      int kk = id / 48;
      int j = (id % 48) * 4;
      int half = (j >= 96) ? 1 : 0;
      int jj = j - half * 96;
      int e = jj >> 5, o = jj & 31;
      float4 v = *(const float4*)(eW + ((size_t)((e * 2 + half) * IN) + k0 + kk) * 32 + o);
      Ws[(j + 0) * 36 + kk] = v.x;
      Ws[(j + 1) * 36 + kk] = v.y;
      Ws[(j + 2) * 36 + kk] = v.z;
      Ws[(j + 3) * 36 + kk] = v.w;
    }
    __syncthreads();
#pragma unroll
    for (int g = 0; g < 8; ++g) {  // kk = 4*g .. 4*g+3
      float4 xv[4], wv[6];
#pragma unroll
      for (int i = 0; i < 4; ++i) xv[i] = *(const float4*)(Xs + (ng * 4 + i) * 32 + 4 * g);
#pragma unroll
      for (int c = 0; c < 6; ++c) wv[c] = *(const float4*)(Ws + (t32 + 32 * c) * 36 + 4 * g);
#pragma unroll
      for (int i = 0; i < 4; ++i)
#pragma unroll
        for (int c = 0; c < 6; ++c) {
          acc[i][c] = fmaf(xv[i].x, wv[c].x, acc[i][c]);
          acc[i][c] = fmaf(xv[i].y, wv[c].y, acc[i][c]);
          acc[i][c] = fmaf(xv[i].z, wv[c].z, acc[i][c]);
          acc[i][c] = fmaf(xv[i].w, wv[c].w, acc[i][c]);
        }
    }
    __syncthreads();
  }
#pragma unroll
  for (int i = 0; i < 4; ++i) {
    int node = base + ng * 4 + i;
    if (node < n) {
#pragma unroll
      for (int c = 0; c < 6; ++c) P[(size_t)node * 192 + t32 + 32 * c] = acc[i][c];
    }
  }
}

// ---------------- edge aggregation (gather over CSR) ----------------

__global__ __launch_bounds__(256) void aggregate_kernel(const float* __restrict__ P,
                                                        const int* __restrict__ rowstart,
                                                        const int* __restrict__ edata,
                                                        const float* __restrict__ eb,
                                                        float* __restrict__ h, int n) {
  int wid = (blockIdx.x * 256 + threadIdx.x) >> 6;
  if (wid >= n) return;
  int lane = threadIdx.x & 63;
  int o = lane & 31, slot = lane >> 5;
  const float* Pd = P + (size_t)wid * 192 + 96;
  float pdb0 = Pd[o] + eb[o];
  float pdb1 = Pd[32 + o] + eb[32 + o];
  float pdb2 = Pd[64 + o] + eb[64 + o];
  float a0 = 0.f, a1 = 0.f, a2 = 0.f;
  int c0 = 0, c1 = 0, c2 = 0;
  int s = rowstart[wid], e = rowstart[wid + 1];
  for (int i = s + slot; i < e; i += 2) {
    int pk = edata[i];  // broadcast within half-wave
    int srcn = pk & 0xFFFF;
    int et = pk >> 16;
    float v = P[(size_t)srcn * 192 + et * 32 + o];  // 128B coalesced per half-wave
    float pb = (et == 0) ? pdb0 : ((et == 1) ? pdb1 : pdb2);
    float m = fmaxf(v + pb, 0.f);
    a0 += (et == 0) ? m : 0.f;
    a1 += (et == 1) ? m : 0.f;
    a2 += (et == 2) ? m : 0.f;
    c0 += (et == 0);
    c1 += (et == 1);
    c2 += (et == 2);
  }
  a0 += __shfl_xor(a0, 32);
  a1 += __shfl_xor(a1, 32);
  a2 += __shfl_xor(a2, 32);
  c0 += __shfl_xor(c0, 32);
  c1 += __shfl_xor(c1, 32);
  c2 += __shfl_xor(c2, 32);
  if (slot == 0) {
    float* hn = h + (size_t)wid * 96;
    hn[o] = a0 / fmaxf((float)c0, 1.f);
    hn[32 + o] = a1 / fmaxf((float)c1, 1.f);
    hn[64 + o] = a2 / fmaxf((float)c2, 1.f);
  }
}

// ---------------- node MLP (type-partitioned) ----------------

template <int OUT>
__global__ __launch_bounds__(256) void mlp2_kernel(const float* __restrict__ H,
                                                   const float* __restrict__ nW,
                                                   const float* __restrict__ nb,
                                                   const int* __restrict__ idxbuf,
                                                   const int* __restrict__ tcnt,
                                                   float* __restrict__ out, int ncap) {
  constexpr int CO = OUT / 32;  // 4 (OUT=128) or 2 (OUT=64)
  constexpr int WP = 36;
  __shared__ float Xs[64 * 32];
  __shared__ float Ws[OUT * WP];

  int c0 = tcnt[0];
  int nb0 = (c0 + 63) >> 6;
  int t, base, cnt;
  if ((int)blockIdx.x < nb0) {
    t = 0; base = blockIdx.x << 6; cnt = c0;
  } else {
    t = 1; base = ((int)blockIdx.x - nb0) << 6; cnt = tcnt[1];
    if (base >= cnt) return;
  }
  const float* W = nW + (size_t)t * 96 * OUT;
  const float* bias = nb + t * OUT;
  const int* il = idxbuf + (size_t)t * ncap;

  const int tx = threadIdx.x;
  const int t32 = tx & 31;
  const int ng = tx >> 5;

  float acc[8][CO];
#pragma unroll
  for (int i = 0; i < 8; ++i)
#pragma unroll
    for (int c = 0; c < CO; ++c) acc[i][c] = 0.f;

  for (int k0 = 0; k0 < 96; k0 += 32) {
    for (int id = tx; id < 512; id += 256) {
      int i = id >> 3, kk4 = (id & 7) * 4;
      float4 v = make_float4(0.f, 0.f, 0.f, 0.f);
      if (base + i < cnt) {
        int row = il[base + i];
        v = *(const float4*)(H + (size_t)row * 96 + k0 + kk4);
      }
      *(float4*)(Xs + i * 32 + kk4) = v;
    }
    for (int id = tx; id < 32 * (OUT / 4); id += 256) {
      int kk = id / (OUT / 4);
      int j4 = (id % (OUT / 4)) * 4;
      float4 v = *(const float4*)(W + (size_t)(k0 + kk) * OUT + j4);
      Ws[(j4 + 0) * WP + kk] = v.x;
      Ws[(j4 + 1) * WP + kk] = v.y;
      Ws[(j4 + 2) * WP + kk] = v.z;
      Ws[(j4 + 3) * WP + kk] = v.w;
    }
    __syncthreads();
#pragma unroll
    for (int g = 0; g < 8; ++g) {
      float4 xv[8], wv[CO];
#pragma unroll
      for (int i = 0; i < 8; ++i) xv[i] = *(const float4*)(Xs + (ng * 8 + i) * 32 + 4 * g);
#pragma unroll
      for (int c = 0; c < CO; ++c) wv[c] = *(const float4*)(Ws + (t32 + 32 * c) * WP + 4 * g);
#pragma unroll
      for (int i = 0; i < 8; ++i)
#pragma unroll
        for (int c = 0; c < CO; ++c) {
          acc[i][c] = fmaf(xv[i].x, wv[c].x, acc[i][c]);
          acc[i][c] = fmaf(xv[i].y, wv[c].y, acc[i][c]);
          acc[i][c] = fmaf(xv[i].z, wv[c].z, acc[i][c]);
          acc[i][c] = fmaf(xv[i].w, wv[c].w, acc[i][c]);
        }
    }
    __syncthreads();
  }

  float bj[CO];
#pragma unroll
  for (int c = 0; c < CO; ++c) bj[c] = bias[t32 + 32 * c];
#pragma unroll
  for (int i = 0; i < 8; ++i) {
    int slot = base + ng * 8 + i;
    if (slot < cnt) {
      int row = il[slot];
#pragma unroll
      for (int c = 0; c < CO; ++c)
        out[(size_t)row * OUT + t32 + 32 * c] = fmaxf(acc[i][c] + bj[c], 0.f);
    }
  }
}

// ---------------- launch ----------------

extern "C" void kernel_launch(void* const* d_in, const int* in_sizes, int n_in,
                              void* d_out, int out_size, void* d_ws, size_t ws_size,
                              hipStream_t stream) {
  const float* nf    = (const float*)d_in[0];
  const int*   eidx  = (const int*)d_in[1];
  const int*   etype = (const int*)d_in[2];
  const int*   ntype = (const int*)d_in[3];
  const float* eW0   = (const float*)d_in[4];
  const float* eb0   = (const float*)d_in[5];
  const float* nW0   = (const float*)d_in[6];
  const float* nb0   = (const float*)d_in[7];
  const float* eW1   = (const float*)d_in[8];
  const float* eb1   = (const float*)d_in[9];
  const float* nW1   = (const float*)d_in[10];
  const float* nb1   = (const float*)d_in[11];
  const int N = in_sizes[3];
  const int E = in_sizes[2];
  const int* srcv = eidx;
  const int* dstv = eidx + E;

  // workspace layout (~74 MB); rank aliases h96, deg8 aliases h64 (CSR build
  // completes before any aggregate/mlp writes those buffers).
  float* P   = (float*)d_ws;                     // N*192
  float* h96 = P + (size_t)N * 192;              // N*96
  float* h64 = h96 + (size_t)N * 96;             // N*64
  int* rowstart = (int*)(h64 + (size_t)N * 64);  // N+1 (padded to N+4)
  int* tcnt     = rowstart + ((N + 4) & ~3);     // 2
  int* bsum     = tcnt + 2;                      // 64
  int* boff     = bsum + 64;                     // 64
  int* idxbuf   = boff + 64;                     // 2*N
  int* edata    = idxbuf + 2 * N;                // E
  int* rank     = (int*)h96;                     // E  (alias)
  int* deg8     = (int*)h64;                     // 8N (alias)

  const int nsb = (N + 1023) / 1024;  // <=64 for N<=65536
  const int egrid = (E + 255) / 256;

  hipMemsetAsync(deg8, 0, (size_t)N * 8 * sizeof(int), stream);
  hipMemsetAsync(tcnt, 0, 2 * sizeof(int), stream);
  rank_kernel<<<egrid, 256, 0, stream>>>(dstv, deg8, rank, E);
  scan1_kernel<<<nsb, 256, 0, stream>>>(deg8, rowstart, bsum, N);
  scan2_kernel<<<1, 64, 0, stream>>>(bsum, boff, nsb, rowstart, N);
  scan3_kernel<<<(N + 255) / 256, 256, 0, stream>>>(rowstart, boff, N);
  fill_kernel<<<egrid, 256, 0, stream>>>(srcv, dstv, etype, rank, rowstart, deg8, edata, E);
  partition_kernel<<<(N + 255) / 256, 256, 0, stream>>>(ntype, idxbuf, tcnt, N, N);

  int pgrid = (N + 31) / 32;
  int agrid = (N + 3) / 4;
  int mgrid = (N + 63) / 64 + 2;

  // layer 0: 128 -> 64
  proj_kernel<128><<<pgrid, 256, 0, stream>>>(nf, eW0, P, N);
  aggregate_kernel<<<agrid, 256, 0, stream>>>(P, rowstart, edata, eb0, h96, N);
  mlp2_kernel<64><<<mgrid, 256, 0, stream>>>(h96, nW0, nb0, idxbuf, tcnt, h64, N);

  // layer 1: 64 -> 128
  proj_kernel<64><<<pgrid, 256, 0, stream>>>(h64, eW1, P, N);
  aggregate_kernel<<<agrid, 256, 0, stream>>>(P, rowstart, edata, eb1, h96, N);
  mlp2_kernel<128><<<mgrid, 256, 0, stream>>>(h96, nW1, nb1, idxbuf, tcnt, (float*)d_out, N);
}

// Round 5
// 415.267 us; speedup vs baseline: 1.0852x; 1.0852x over previous
//
#include <hip/hip_runtime.h>

// GNN: N=50000 nodes, E=800000 edges, IN=128, HID=64, OUT=128, EH=32, 3 etypes, 2 ntypes.
//
// Strategy:
//   feat @ eW[e] = nf[src] @ eW[e][:IN] + nf[dst] @ eW[e][IN:]
//   => per-node projections P[n][192], per-edge work = 32 adds + relu + reg accumulation
//      (gather over CSR-by-dst). Node MLP type-partitioned.
//
// R1: multi-block scan (was 77 us single-block).
// R2: mlp: type-partitioned; R3: CSR via replicated-rank + atomic-free scatter (kept).
// R4: R3's WP=36 transposed-W LDS layout was misaligned (odd-row float4) and
//     bank-hostile (36-word lane stride; 2.2e7 conflict cycles/dispatch).
//     Conflict-free b128 rule: lanes must access CONSECUTIVE 16B quads.
//     New layout: W quads [(g*J + j)*4 + w] = W[k0+4g+w][j]; wv lane stride = 4
//     words (aligned, conflict-free); staging writes lane-consecutive quads.
//     proj restored to 64-node tile with this inner loop; mlp2 same fix.

// ---------------- CSR build ----------------

__global__ __launch_bounds__(256) void rank_kernel(const int* __restrict__ dst,
                                                   int* __restrict__ deg8,
                                                   int* __restrict__ rank, int E) {
  int i = blockIdx.x * 256 + threadIdx.x;
  if (i < E) {
    int d = dst[i];
    int r = (i >> 8) & 7;
    rank[i] = atomicAdd(&deg8[d * 8 + r], 1);
  }
}

__global__ __launch_bounds__(256) void scan1_kernel(int* __restrict__ deg8,
                                                    int* __restrict__ rowstart,
                                                    int* __restrict__ bsum, int n) {
  __shared__ int tmp[256];
  int t = threadIdx.x;
  int base = blockIdx.x * 1024 + t * 4;
  int vdeg[4];
#pragma unroll
  for (int q = 0; q < 4; ++q) {
    int v = base + q;
    int d = 0;
    if (v < n) {
      int4 a = *(int4*)(deg8 + (size_t)v * 8);
      int4 b = *(int4*)(deg8 + (size_t)v * 8 + 4);
      int p1 = a.x, p2 = p1 + a.y, p3 = p2 + a.z, p4 = p3 + a.w;
      int p5 = p4 + b.x, p6 = p5 + b.y, p7 = p6 + b.z;
      d = p7 + b.w;
      *(int4*)(deg8 + (size_t)v * 8) = make_int4(0, p1, p2, p3);
      *(int4*)(deg8 + (size_t)v * 8 + 4) = make_int4(p4, p5, p6, p7);
    }
    vdeg[q] = d;
  }
  int s = vdeg[0] + vdeg[1] + vdeg[2] + vdeg[3];
  tmp[t] = s;
  __syncthreads();
  for (int off = 1; off < 256; off <<= 1) {
    int u = (t >= off) ? tmp[t - off] : 0;
    __syncthreads();
    tmp[t] += u;
    __syncthreads();
  }
  int excl = tmp[t] - s;
  if (base < n)     rowstart[base]     = excl;
  if (base + 1 < n) rowstart[base + 1] = excl + vdeg[0];
  if (base + 2 < n) rowstart[base + 2] = excl + vdeg[0] + vdeg[1];
  if (base + 3 < n) rowstart[base + 3] = excl + vdeg[0] + vdeg[1] + vdeg[2];
  if (t == 255) bsum[blockIdx.x] = tmp[255];
}

__global__ __launch_bounds__(64) void scan2_kernel(const int* __restrict__ bsum,
                                                   int* __restrict__ boff, int nb,
                                                   int* __restrict__ rowstart, int n) {
  int lane = threadIdx.x;
  int v = (lane < nb) ? bsum[lane] : 0;
  int incl = v;
  for (int off = 1; off < 64; off <<= 1) {
    int u = __shfl_up(incl, off, 64);
    if (lane >= off) incl += u;
  }
  if (lane < nb) boff[lane] = incl - v;
  if (lane == 63) rowstart[n] = incl;
}

__global__ __launch_bounds__(256) void scan3_kernel(int* __restrict__ rowstart,
                                                    const int* __restrict__ boff, int n) {
  int i = blockIdx.x * 256 + threadIdx.x;
  if (i < n) rowstart[i] += boff[i >> 10];
}

__global__ __launch_bounds__(256) void fill_kernel(const int* __restrict__ src,
                                                   const int* __restrict__ dst,
                                                   const int* __restrict__ etype,
                                                   const int* __restrict__ rank,
                                                   const int* __restrict__ rowstart,
                                                   const int* __restrict__ deg8,
                                                   int* __restrict__ edata, int E) {
  int i = blockIdx.x * 256 + threadIdx.x;
  if (i < E) {
    int d = dst[i];
    int r = (i >> 8) & 7;
    int pos = rowstart[d] + deg8[d * 8 + r] + rank[i];
    edata[pos] = (etype[i] << 16) | src[i];  // src < 65536 OK (N=50000)
  }
}

// ---------------- node partition by type ----------------

__global__ __launch_bounds__(256) void partition_kernel(const int* __restrict__ ntype,
                                                        int* __restrict__ idxbuf,
                                                        int* __restrict__ tcnt,
                                                        int n, int ncap) {
  int i = blockIdx.x * 256 + threadIdx.x;
  int lane = threadIdx.x & 63;
  int t = (i < n) ? ntype[i] : -1;
  unsigned long long m0 = __ballot(t == 0);
  unsigned long long m1 = __ballot(t == 1);
  int b0 = 0, b1 = 0;
  if (lane == 0) {
    b0 = atomicAdd(&tcnt[0], (int)__popcll(m0));
    b1 = atomicAdd(&tcnt[1], (int)__popcll(m1));
  }
  b0 = __shfl(b0, 0);
  b1 = __shfl(b1, 0);
  unsigned long long below = (1ull << lane) - 1ull;
  if (t == 0) idxbuf[b0 + (int)__popcll(m0 & below)] = i;
  else if (t == 1) idxbuf[ncap + b1 + (int)__popcll(m1 & below)] = i;
}

// ---------------- node projection GEMM: P[N,192] = X[N,IN] @ W2[IN,192] ----------------
// 64-node x 192 tile, BK=32. Ws quad-transposed: quad (g,j) holds W2[k0+4g+w][j],
// stored at (g*192+j)*4 -> wv lane stride 4 words (aligned conflict-free b128).
// Thread: 8 nodes (b128 broadcast xv) x 6 outputs.

template <int IN>
__global__ __launch_bounds__(256) void proj_kernel(const float* __restrict__ X,
                                                   const float* __restrict__ eW,
                                                   float* __restrict__ P, int n) {
  __shared__ float Xs[64 * 32];    // [node][kk]  8 KB
  __shared__ float Ws[8 * 192 * 4];  // [g][j][w]  24 KB
  const int tx = threadIdx.x;
  const int t32 = tx & 31;
  const int ng = tx >> 5;  // 8 groups x 8 nodes
  const int base = blockIdx.x * 64;
  float acc[8][6];
#pragma unroll
  for (int i = 0; i < 8; ++i)
#pragma unroll
    for (int c = 0; c < 6; ++c) acc[i][c] = 0.f;

  for (int k0 = 0; k0 < IN; k0 += 32) {
    // stage X: [node][kk] pitch 32; lane-consecutive quads on write
    for (int id = tx; id < 512; id += 256) {
      int i = id >> 3, kk4 = (id & 7) * 4;
      int node = base + i;
      float4 v = make_float4(0.f, 0.f, 0.f, 0.f);
      if (node < n) v = *(const float4*)(X + (size_t)node * IN + k0 + kk4);
      *(float4*)(Xs + i * 32 + kk4) = v;
    }
    // stage W quad-transposed: 1536 quads; thread reads 4 k-strided globals (L2-hot),
    // writes one b128 at id*4 (lane-consecutive quads, conflict-free)
    for (int id = tx; id < 1536; id += 256) {
      int g = id / 192;       // kk quad
      int j = id % 192;       // output col
      int half = (j >= 96) ? 1 : 0;
      int jj = j - half * 96;
      int e = jj >> 5, o = jj & 31;
      const float* wp = eW + ((size_t)((e * 2 + half) * IN) + k0 + 4 * g) * 32 + o;
      float4 v = make_float4(wp[0], wp[32], wp[64], wp[96]);
      *(float4*)(Ws + (size_t)id * 4) = v;
    }
    __syncthreads();
#pragma unroll
    for (int g = 0; g < 8; ++g) {
      float4 xv[8], wv[6];
#pragma unroll
      for (int i = 0; i < 8; ++i) xv[i] = *(const float4*)(Xs + (ng * 8 + i) * 32 + 4 * g);
#pragma unroll
      for (int c = 0; c < 6; ++c) wv[c] = *(const float4*)(Ws + ((size_t)g * 192 + t32 + 32 * c) * 4);
#pragma unroll
      for (int i = 0; i < 8; ++i)
#pragma unroll
        for (int c = 0; c < 6; ++c) {
          acc[i][c] = fmaf(xv[i].x, wv[c].x, acc[i][c]);
          acc[i][c] = fmaf(xv[i].y, wv[c].y, acc[i][c]);
          acc[i][c] = fmaf(xv[i].z, wv[c].z, acc[i][c]);
          acc[i][c] = fmaf(xv[i].w, wv[c].w, acc[i][c]);
        }
    }
    __syncthreads();
  }
#pragma unroll
  for (int i = 0; i < 8; ++i) {
    int node = base + ng * 8 + i;
    if (node < n) {
#pragma unroll
      for (int c = 0; c < 6; ++c) P[(size_t)node * 192 + t32 + 32 * c] = acc[i][c];
    }
  }
}

// ---------------- edge aggregation (gather over CSR) ----------------

__global__ __launch_bounds__(256) void aggregate_kernel(const float* __restrict__ P,
                                                        const int* __restrict__ rowstart,
                                                        const int* __restrict__ edata,
                                                        const float* __restrict__ eb,
                                                        float* __restrict__ h, int n) {
  int wid = (blockIdx.x * 256 + threadIdx.x) >> 6;
  if (wid >= n) return;
  int lane = threadIdx.x & 63;
  int o = lane & 31, slot = lane >> 5;
  const float* Pd = P + (size_t)wid * 192 + 96;
  float pdb0 = Pd[o] + eb[o];
  float pdb1 = Pd[32 + o] + eb[32 + o];
  float pdb2 = Pd[64 + o] + eb[64 + o];
  float a0 = 0.f, a1 = 0.f, a2 = 0.f;
  int c0 = 0, c1 = 0, c2 = 0;
  int s = rowstart[wid], e = rowstart[wid + 1];
  for (int i = s + slot; i < e; i += 2) {
    int pk = edata[i];
    int srcn = pk & 0xFFFF;
    int et = pk >> 16;
    float v = P[(size_t)srcn * 192 + et * 32 + o];
    float pb = (et == 0) ? pdb0 : ((et == 1) ? pdb1 : pdb2);
    float m = fmaxf(v + pb, 0.f);
    a0 += (et == 0) ? m : 0.f;
    a1 += (et == 1) ? m : 0.f;
    a2 += (et == 2) ? m : 0.f;
    c0 += (et == 0);
    c1 += (et == 1);
    c2 += (et == 2);
  }
  a0 += __shfl_xor(a0, 32);
  a1 += __shfl_xor(a1, 32);
  a2 += __shfl_xor(a2, 32);
  c0 += __shfl_xor(c0, 32);
  c1 += __shfl_xor(c1, 32);
  c2 += __shfl_xor(c2, 32);
  if (slot == 0) {
    float* hn = h + (size_t)wid * 96;
    hn[o] = a0 / fmaxf((float)c0, 1.f);
    hn[32 + o] = a1 / fmaxf((float)c1, 1.f);
    hn[64 + o] = a2 / fmaxf((float)c2, 1.f);
  }
}

// ---------------- node MLP (type-partitioned), quad-transposed Ws ----------------

template <int OUT>
__global__ __launch_bounds__(256) void mlp2_kernel(const float* __restrict__ H,
                                                   const float* __restrict__ nW,
                                                   const float* __restrict__ nb,
                                                   const int* __restrict__ idxbuf,
                                                   const int* __restrict__ tcnt,
                                                   float* __restrict__ out, int ncap) {
  constexpr int CO = OUT / 32;  // 4 (OUT=128) or 2 (OUT=64)
  __shared__ float Xs[64 * 32];       // 8 KB
  __shared__ float Ws[8 * OUT * 4];   // [g][j][w]  16 KB (OUT=128)

  int c0 = tcnt[0];
  int nb0 = (c0 + 63) >> 6;
  int t, base, cnt;
  if ((int)blockIdx.x < nb0) {
    t = 0; base = blockIdx.x << 6; cnt = c0;
  } else {
    t = 1; base = ((int)blockIdx.x - nb0) << 6; cnt = tcnt[1];
    if (base >= cnt) return;
  }
  const float* W = nW + (size_t)t * 96 * OUT;
  const float* bias = nb + t * OUT;
  const int* il = idxbuf + (size_t)t * ncap;

  const int tx = threadIdx.x;
  const int t32 = tx & 31;
  const int ng = tx >> 5;

  float acc[8][CO];
#pragma unroll
  for (int i = 0; i < 8; ++i)
#pragma unroll
    for (int c = 0; c < CO; ++c) acc[i][c] = 0.f;

  for (int k0 = 0; k0 < 96; k0 += 32) {
    for (int id = tx; id < 512; id += 256) {
      int i = id >> 3, kk4 = (id & 7) * 4;
      float4 v = make_float4(0.f, 0.f, 0.f, 0.f);
      if (base + i < cnt) {
        int row = il[base + i];
        v = *(const float4*)(H + (size_t)row * 96 + k0 + kk4);
      }
      *(float4*)(Xs + i * 32 + kk4) = v;
    }
    // W quads: (g,j) holds W[k0+4g+w][j]; 8*OUT quads
    for (int id = tx; id < 8 * OUT; id += 256) {
      int g = id / OUT;
      int j = id % OUT;
      const float* wp = W + (size_t)(k0 + 4 * g) * OUT + j;
      float4 v = make_float4(wp[0], wp[OUT], wp[2 * OUT], wp[3 * OUT]);
      *(float4*)(Ws + (size_t)id * 4) = v;
    }
    __syncthreads();
#pragma unroll
    for (int g = 0; g < 8; ++g) {
      float4 xv[8], wv[CO];
#pragma unroll
      for (int i = 0; i < 8; ++i) xv[i] = *(const float4*)(Xs + (ng * 8 + i) * 32 + 4 * g);
#pragma unroll
      for (int c = 0; c < CO; ++c) wv[c] = *(const float4*)(Ws + ((size_t)g * OUT + t32 + 32 * c) * 4);
#pragma unroll
      for (int i = 0; i < 8; ++i)
#pragma unroll
        for (int c = 0; c < CO; ++c) {
          acc[i][c] = fmaf(xv[i].x, wv[c].x, acc[i][c]);
          acc[i][c] = fmaf(xv[i].y, wv[c].y, acc[i][c]);
          acc[i][c] = fmaf(xv[i].z, wv[c].z, acc[i][c]);
          acc[i][c] = fmaf(xv[i].w, wv[c].w, acc[i][c]);
        }
    }
    __syncthreads();
  }

  float bj[CO];
#pragma unroll
  for (int c = 0; c < CO; ++c) bj[c] = bias[t32 + 32 * c];
#pragma unroll
  for (int i = 0; i < 8; ++i) {
    int slot = base + ng * 8 + i;
    if (slot < cnt) {
      int row = il[slot];
#pragma unroll
      for (int c = 0; c < CO; ++c)
        out[(size_t)row * OUT + t32 + 32 * c] = fmaxf(acc[i][c] + bj[c], 0.f);
    }
  }
}

// ---------------- launch ----------------

extern "C" void kernel_launch(void* const* d_in, const int* in_sizes, int n_in,
                              void* d_out, int out_size, void* d_ws, size_t ws_size,
                              hipStream_t stream) {
  const float* nf    = (const float*)d_in[0];
  const int*   eidx  = (const int*)d_in[1];
  const int*   etype = (const int*)d_in[2];
  const int*   ntype = (const int*)d_in[3];
  const float* eW0   = (const float*)d_in[4];
  const float* eb0   = (const float*)d_in[5];
  const float* nW0   = (const float*)d_in[6];
  const float* nb0   = (const float*)d_in[7];
  const float* eW1   = (const float*)d_in[8];
  const float* eb1   = (const float*)d_in[9];
  const float* nW1   = (const float*)d_in[10];
  const float* nb1   = (const float*)d_in[11];
  const int N = in_sizes[3];
  const int E = in_sizes[2];
  const int* srcv = eidx;
  const int* dstv = eidx + E;

  // workspace layout; rank aliases h96, deg8 aliases h64 (CSR build completes
  // before aggregate/mlp write those buffers — stream-ordered).
  float* P   = (float*)d_ws;                     // N*192
  float* h96 = P + (size_t)N * 192;              // N*96
  float* h64 = h96 + (size_t)N * 96;             // N*64
  int* rowstart = (int*)(h64 + (size_t)N * 64);  // N+1 (padded)
  int* tcnt     = rowstart + ((N + 4) & ~3);     // 2
  int* bsum     = tcnt + 2;                      // 64
  int* boff     = bsum + 64;                     // 64
  int* idxbuf   = boff + 64;                     // 2*N
  int* edata    = idxbuf + 2 * N;                // E
  int* rank     = (int*)h96;                     // E  (alias)
  int* deg8     = (int*)h64;                     // 8N (alias)

  const int nsb = (N + 1023) / 1024;
  const int egrid = (E + 255) / 256;

  hipMemsetAsync(deg8, 0, (size_t)N * 8 * sizeof(int), stream);
  hipMemsetAsync(tcnt, 0, 2 * sizeof(int), stream);
  rank_kernel<<<egrid, 256, 0, stream>>>(dstv, deg8, rank, E);
  scan1_kernel<<<nsb, 256, 0, stream>>>(deg8, rowstart, bsum, N);
  scan2_kernel<<<1, 64, 0, stream>>>(bsum, boff, nsb, rowstart, N);
  scan3_kernel<<<(N + 255) / 256, 256, 0, stream>>>(rowstart, boff, N);
  fill_kernel<<<egrid, 256, 0, stream>>>(srcv, dstv, etype, rank, rowstart, deg8, edata, E);
  partition_kernel<<<(N + 255) / 256, 256, 0, stream>>>(ntype, idxbuf, tcnt, N, N);

  int pgrid = (N + 63) / 64;
  int agrid = (N + 3) / 4;
  int mgrid = (N + 63) / 64 + 2;

  // layer 0: 128 -> 64
  proj_kernel<128><<<pgrid, 256, 0, stream>>>(nf, eW0, P, N);
  aggregate_kernel<<<agrid, 256, 0, stream>>>(P, rowstart, edata, eb0, h96, N);
  mlp2_kernel<64><<<mgrid, 256, 0, stream>>>(h96, nW0, nb0, idxbuf, tcnt, h64, N);

  // layer 1: 64 -> 128
  proj_kernel<64><<<pgrid, 256, 0, stream>>>(h64, eW1, P, N);
  aggregate_kernel<<<agrid, 256, 0, stream>>>(P, rowstart, edata, eb1, h96, N);
  mlp2_kernel<128><<<mgrid, 256, 0, stream>>>(h96, nW1, nb1, idxbuf, tcnt, (float*)d_out, N);
}